// Round 1
// baseline (1285.880 us; speedup 1.0000x reference)
//
#include <hip/hip_runtime.h>
#include <hip/hip_bf16.h>

#define T_TOK 8192
#define DH 1024
#define DFFN 4096
#define NEXP 8

typedef __attribute__((ext_vector_type(8))) short short8;
typedef __attribute__((ext_vector_type(4))) float f32x4;
typedef __attribute__((ext_vector_type(8))) unsigned short ushortx8;
typedef __attribute__((ext_vector_type(4))) unsigned short ushortx4;

// ---------------- ws layout (bytes) ----------------
#define WS_COUNT   0                   // int[8]   (memset 0)
#define WS_CURSOR  32                  // int[8]   (set by prefix kernel)
#define WS_ESUM    64                  // float[8] (memset 0)
#define WS_PREFIX  96                  // int[8]
#define WS_IDX     128                 // int[2*T_TOK]
#define WS_WPAIR   (128 + 65536)       // float[2*T_TOK]
#define WS_ROWTOK  (128 + 131072)      // int[16640]
#define WS_ROWW    (WS_ROWTOK + 66560) // float[16640]
#define WS_H       270336              // ushort[16384*4096]  bf16, 4096B-aligned

__device__ inline unsigned short f2bf(float f) {
    unsigned u = __float_as_uint(f);
    u += 0x7fffu + ((u >> 16) & 1u);   // RNE
    return (unsigned short)(u >> 16);
}

__device__ inline ushortx8 pack8(float4 a, float4 b) {
    ushortx8 r;
    r[0] = f2bf(a.x); r[1] = f2bf(a.y); r[2] = f2bf(a.z); r[3] = f2bf(a.w);
    r[4] = f2bf(b.x); r[5] = f2bf(b.y); r[6] = f2bf(b.z); r[7] = f2bf(b.w);
    return r;
}

// ---------------- gating: one wave per token ----------------
__global__ __launch_bounds__(256) void gate_kernel(
        const float* __restrict__ x, const float* __restrict__ Wg,
        int* __restrict__ cnt, float* __restrict__ esum,
        int* __restrict__ idx_pair, float* __restrict__ w_pair) {
    int wid = threadIdx.x >> 6, lane = threadIdx.x & 63;
    int t = blockIdx.x * 4 + wid;
    const float4* xv = (const float4*)(x + (size_t)t * DH);
    const float4* wv = (const float4*)Wg;
    float acc[NEXP];
#pragma unroll
    for (int e = 0; e < NEXP; e++) acc[e] = 0.f;
#pragma unroll
    for (int c = 0; c < 4; c++) {
        int fi = c * 64 + lane;
        float4 xe = xv[fi];
#pragma unroll
        for (int e = 0; e < NEXP; e++) {
            float4 we = wv[e * 256 + fi];
            acc[e] += xe.x * we.x + xe.y * we.y + xe.z * we.z + xe.w * we.w;
        }
    }
#pragma unroll
    for (int e = 0; e < NEXP; e++) {
#pragma unroll
        for (int off = 32; off > 0; off >>= 1)
            acc[e] += __shfl_xor(acc[e], off, 64);
    }
    if (lane == 0) {
        float v0 = -1e30f, v1 = -1e30f;
        int i0 = 0, i1 = 0;
#pragma unroll
        for (int e = 0; e < NEXP; e++) {
            float l = acc[e];
            if (l > v0) { v1 = v0; i1 = i0; v0 = l; i0 = e; }
            else if (l > v1) { v1 = l; i1 = e; }
        }
        float e1 = __expf(v1 - v0);
        float w0 = 1.0f / (1.0f + e1);
        float w1 = e1 / (1.0f + e1);
        idx_pair[2 * t] = i0; idx_pair[2 * t + 1] = i1;
        w_pair[2 * t] = w0;   w_pair[2 * t + 1] = w1;
        atomicAdd(&cnt[i0], 1); atomicAdd(&cnt[i1], 1);
        atomicAdd(&esum[i0], w0); atomicAdd(&esum[i1], w1);
    }
}

// ---------------- prefix scan + load-balance loss ----------------
__global__ void prefix_lb_kernel(const int* __restrict__ cnt, int* __restrict__ prefix,
                                 int* __restrict__ cursor, const float* __restrict__ esum,
                                 float* __restrict__ lb_out) {
    if (threadIdx.x == 0) {
        int run = 0;
        for (int e = 0; e < NEXP; e++) { prefix[e] = run; cursor[e] = run; run += cnt[e]; }
        float mu = 0.f, us[NEXP];
        for (int e = 0; e < NEXP; e++) { us[e] = esum[e] * (1.0f / T_TOK); mu += us[e]; }
        mu *= (1.0f / NEXP);
        float var = 0.f;
        for (int e = 0; e < NEXP; e++) { float d = us[e] - mu; var += d * d; }
        var *= (1.0f / (NEXP - 1));
        lb_out[0] = 0.01f * var;
    }
}

// ---------------- scatter tokens to per-expert compact rows ----------------
__global__ __launch_bounds__(256) void scatter_kernel(
        const int* __restrict__ idx_pair, const float* __restrict__ w_pair,
        int* __restrict__ cursor, int* __restrict__ row_tok, float* __restrict__ row_w) {
    int t = blockIdx.x * 256 + threadIdx.x;
#pragma unroll
    for (int k = 0; k < 2; k++) {
        int e = idx_pair[2 * t + k];
        int slot = atomicAdd(&cursor[e], 1);
        row_tok[slot] = t;
        row_w[slot] = w_pair[2 * t + k];
    }
}

// ---------------- FFN1: H = gelu(x[gathered] @ W1[e] + b1[e]), bf16 MFMA ----------------
__global__ __launch_bounds__(256, 2) void ffn1_kernel(
        const float* __restrict__ x, const float* __restrict__ W1,
        const float* __restrict__ b1, const int* __restrict__ hdr,
        const int* __restrict__ row_tok, unsigned short* __restrict__ H) {
    int e = blockIdx.z;
    int cntv = hdr[e];
    int rt = blockIdx.y;
    int valid = cntv - rt * 128;
    if (valid <= 0) return;
    if (valid > 128) valid = 128;
    int base = hdr[24 + e] + rt * 128;
    int f0 = blockIdx.x * 128;

    __shared__ unsigned short Alds[128 * 40];
    __shared__ unsigned short Blds[128 * 40];
    __shared__ int ltok[128];

    int tid = threadIdx.x;
    if (tid < 128) ltok[tid] = (tid < valid) ? row_tok[base + tid] : 0;
    __syncthreads();

    f32x4 acc[4][4];
#pragma unroll
    for (int i = 0; i < 4; i++)
#pragma unroll
        for (int j = 0; j < 4; j++) acc[i][j] = (f32x4)(0.f);

    int lane = tid & 63;
    int wv = tid >> 6;
    int wm = (wv & 1) * 64;
    int wn = (wv >> 1) * 64;
    int lr = lane & 15, lg = lane >> 4;

    int ar = tid >> 1;
    int akoff = (tid & 1) * 16;
    const float* abase = x + (size_t)ltok[ar] * DH + akoff;
    int bf = tid & 127;
    int bkg = tid >> 7;

    for (int k0 = 0; k0 < DH; k0 += 32) {
        const float4* ap = (const float4*)(abase + k0);
        float4 a0 = ap[0], a1 = ap[1], a2 = ap[2], a3 = ap[3];
        *(ushortx8*)&Alds[ar * 40 + akoff] = pack8(a0, a1);
        *(ushortx8*)&Alds[ar * 40 + akoff + 8] = pack8(a2, a3);
#pragma unroll
        for (int it = 0; it < 4; it++) {
            int kk = (bkg + it * 2) * 4;
            const float* bp = W1 + ((size_t)e * DH + (k0 + kk)) * DFFN + f0 + bf;
            float b0 = bp[0], b1v = bp[DFFN], b2v = bp[2 * DFFN], b3v = bp[3 * DFFN];
            ushortx4 pb;
            pb[0] = f2bf(b0); pb[1] = f2bf(b1v); pb[2] = f2bf(b2v); pb[3] = f2bf(b3v);
            *(ushortx4*)&Blds[bf * 40 + kk] = pb;
        }
        __syncthreads();
        short8 af[4], bfr[4];
#pragma unroll
        for (int i = 0; i < 4; i++)
            af[i] = *(const short8*)&Alds[(wm + i * 16 + lr) * 40 + lg * 8];
#pragma unroll
        for (int j = 0; j < 4; j++)
            bfr[j] = *(const short8*)&Blds[(wn + j * 16 + lr) * 40 + lg * 8];
#pragma unroll
        for (int i = 0; i < 4; i++)
#pragma unroll
            for (int j = 0; j < 4; j++)
                acc[i][j] = __builtin_amdgcn_mfma_f32_16x16x32_bf16(af[i], bfr[j], acc[i][j], 0, 0, 0);
        __syncthreads();
    }
#pragma unroll
    for (int i = 0; i < 4; i++) {
#pragma unroll
        for (int r = 0; r < 4; r++) {
            int mm = wm + i * 16 + lg * 4 + r;
            if (mm < valid) {
                size_t rowoff = (size_t)(base + mm) * DFFN + f0;
#pragma unroll
                for (int j = 0; j < 4; j++) {
                    int n = wn + j * 16 + lr;
                    float v = acc[i][j][r] + b1[e * DFFN + f0 + n];
                    v = 0.5f * v * (1.0f + erff(v * 0.70710678118f));
                    H[rowoff + n] = f2bf(v);
                }
            }
        }
    }
}

// ---------------- FFN2: out[tok] += w * (H @ W2[e] + b2[e]) ----------------
__global__ __launch_bounds__(256, 2) void ffn2_kernel(
        const unsigned short* __restrict__ H, const float* __restrict__ W2,
        const float* __restrict__ b2, const int* __restrict__ hdr,
        const int* __restrict__ row_tok, const float* __restrict__ row_w,
        float* __restrict__ out) {
    int e = blockIdx.z;
    int cntv = hdr[e];
    int rt = blockIdx.y;
    int valid = cntv - rt * 128;
    if (valid <= 0) return;
    if (valid > 128) valid = 128;
    int base = hdr[24 + e] + rt * 128;
    int d0 = blockIdx.x * 128;

    __shared__ unsigned short Alds[128 * 40];
    __shared__ unsigned short Blds[128 * 40];
    __shared__ int ltok[128];
    __shared__ float lw[128];

    int tid = threadIdx.x;
    if (tid < 128) {
        bool v = tid < valid;
        ltok[tid] = v ? row_tok[base + tid] : 0;
        lw[tid] = v ? row_w[base + tid] : 0.f;
    }
    __syncthreads();

    f32x4 acc[4][4];
#pragma unroll
    for (int i = 0; i < 4; i++)
#pragma unroll
        for (int j = 0; j < 4; j++) acc[i][j] = (f32x4)(0.f);

    int lane = tid & 63;
    int wv = tid >> 6;
    int wm = (wv & 1) * 64;
    int wn = (wv >> 1) * 64;
    int lr = lane & 15, lg = lane >> 4;

    int ar = tid >> 1;
    int akoff = (tid & 1) * 16;
    int arow = (ar < valid) ? ar : 0;
    const unsigned short* abase = H + (size_t)(base + arow) * DFFN + akoff;
    int bf = tid & 127;
    int bkg = tid >> 7;

    for (int k0 = 0; k0 < DFFN; k0 += 32) {
        ushortx8 h0 = *(const ushortx8*)(abase + k0);
        ushortx8 h1 = *(const ushortx8*)(abase + k0 + 8);
        *(ushortx8*)&Alds[ar * 40 + akoff] = h0;
        *(ushortx8*)&Alds[ar * 40 + akoff + 8] = h1;
#pragma unroll
        for (int it = 0; it < 4; it++) {
            int kk = (bkg + it * 2) * 4;
            const float* bp = W2 + ((size_t)e * DFFN + (k0 + kk)) * DH + d0 + bf;
            float b0 = bp[0], b1v = bp[DH], b2v = bp[2 * DH], b3v = bp[3 * DH];
            ushortx4 pb;
            pb[0] = f2bf(b0); pb[1] = f2bf(b1v); pb[2] = f2bf(b2v); pb[3] = f2bf(b3v);
            *(ushortx4*)&Blds[bf * 40 + kk] = pb;
        }
        __syncthreads();
        short8 af[4], bfr[4];
#pragma unroll
        for (int i = 0; i < 4; i++)
            af[i] = *(const short8*)&Alds[(wm + i * 16 + lr) * 40 + lg * 8];
#pragma unroll
        for (int j = 0; j < 4; j++)
            bfr[j] = *(const short8*)&Blds[(wn + j * 16 + lr) * 40 + lg * 8];
#pragma unroll
        for (int i = 0; i < 4; i++)
#pragma unroll
            for (int j = 0; j < 4; j++)
                acc[i][j] = __builtin_amdgcn_mfma_f32_16x16x32_bf16(af[i], bfr[j], acc[i][j], 0, 0, 0);
        __syncthreads();
    }
#pragma unroll
    for (int i = 0; i < 4; i++) {
#pragma unroll
        for (int r = 0; r < 4; r++) {
            int mm = wm + i * 16 + lg * 4 + r;
            if (mm < valid) {
                int tok = ltok[mm];
                float wgt = lw[mm];
                float* orow = out + (size_t)tok * DH + d0;
#pragma unroll
                for (int j = 0; j < 4; j++) {
                    int n = wn + j * 16 + lr;
                    float v = acc[i][j][r] + b2[e * DH + d0 + n];
                    unsafeAtomicAdd(&orow[n], wgt * v);
                }
            }
        }
    }
}

extern "C" void kernel_launch(void* const* d_in, const int* in_sizes, int n_in,
                              void* d_out, int out_size, void* d_ws, size_t ws_size,
                              hipStream_t stream) {
    const float* x  = (const float*)d_in[0];
    const float* Wg = (const float*)d_in[1];
    const float* W1 = (const float*)d_in[2];
    const float* b1 = (const float*)d_in[3];
    const float* W2 = (const float*)d_in[4];
    const float* b2 = (const float*)d_in[5];
    float* out = (float*)d_out;
    char* ws = (char*)d_ws;

    int* cnt      = (int*)(ws + WS_COUNT);
    int* cursor   = (int*)(ws + WS_CURSOR);
    float* esum   = (float*)(ws + WS_ESUM);
    int* prefix   = (int*)(ws + WS_PREFIX);
    int* idx_pair = (int*)(ws + WS_IDX);
    float* w_pair = (float*)(ws + WS_WPAIR);
    int* row_tok  = (int*)(ws + WS_ROWTOK);
    float* row_w  = (float*)(ws + WS_ROWW);
    unsigned short* H = (unsigned short*)(ws + WS_H);

    hipMemsetAsync(ws, 0, 128, stream);
    hipMemsetAsync(d_out, 0, (size_t)out_size * sizeof(float), stream);

    gate_kernel<<<T_TOK / 4, 256, 0, stream>>>(x, Wg, cnt, esum, idx_pair, w_pair);
    prefix_lb_kernel<<<1, 64, 0, stream>>>(cnt, prefix, cursor, esum,
                                           out + (size_t)T_TOK * DH);
    scatter_kernel<<<T_TOK / 256, 256, 0, stream>>>(idx_pair, w_pair, cursor, row_tok, row_w);
    ffn1_kernel<<<dim3(DFFN / 128, T_TOK / 128, NEXP), 256, 0, stream>>>(
        x, W1, b1, (const int*)ws, row_tok, H);
    ffn2_kernel<<<dim3(DH / 128, T_TOK / 128, NEXP), 256, 0, stream>>>(
        H, W2, b2, (const int*)ws, row_tok, row_w, out);
}

// Round 2
// 1201.411 us; speedup vs baseline: 1.0703x; 1.0703x over previous
//
#include <hip/hip_runtime.h>
#include <hip/hip_bf16.h>
#include <math.h>

#define T_TOK 8192
#define DH 1024
#define DFFN 4096
#define NEXP 8

typedef __attribute__((ext_vector_type(8))) short short8;
typedef __attribute__((ext_vector_type(4))) float f32x4;
typedef __attribute__((ext_vector_type(4))) unsigned short ushortx4;

typedef const __attribute__((address_space(1))) void* gp1_t;
typedef __attribute__((address_space(3))) void* lp3_t;

__device__ __forceinline__ void gl_lds16(const void* g, void* l) {
    __builtin_amdgcn_global_load_lds((gp1_t)g, (lp3_t)l, 16, 0, 0);
}

// chunk swizzle: spreads ds_read_b128 fragment reads across all 32 banks
__device__ __forceinline__ int swz(int r) { return (r ^ (r >> 2)) & 3; }

__device__ __forceinline__ unsigned short f2bf(float f) {
    unsigned u = __float_as_uint(f);
    u += 0x7fffu + ((u >> 16) & 1u);   // RNE
    return (unsigned short)(u >> 16);
}

// ---------------- ws layout (bytes) ----------------
#define WS_COUNT   0                   // int[8]   (memset 0)
#define WS_CURSOR  32                  // int[8]
#define WS_ESUM    64                  // float[8] (memset 0)
#define WS_PREFIX  96                  // int[8]
#define WS_IDX     128                 // int[2*T_TOK]
#define WS_WPAIR   (128 + 65536)       // float[2*T_TOK]
#define WS_ROWTOK  (128 + 131072)      // int[16640]
#define WS_ROWW    (WS_ROWTOK + 66560) // float[16640]
#define WS_XB      270336              // bf16[8192][1024] = 16 MB

// ---------------- gating: one wave per token; also emits x as bf16 ----------------
__global__ __launch_bounds__(256) void gate_kernel(
        const float* __restrict__ x, const float* __restrict__ Wg,
        int* __restrict__ cnt, float* __restrict__ esum,
        int* __restrict__ idx_pair, float* __restrict__ w_pair,
        unsigned short* __restrict__ Xb) {
    int wid = threadIdx.x >> 6, lane = threadIdx.x & 63;
    int t = blockIdx.x * 4 + wid;
    const float4* xv = (const float4*)(x + (size_t)t * DH);
    const float4* wv = (const float4*)Wg;
    float acc[NEXP];
#pragma unroll
    for (int e = 0; e < NEXP; e++) acc[e] = 0.f;
#pragma unroll
    for (int c = 0; c < 4; c++) {
        int fi = c * 64 + lane;
        float4 xe = xv[fi];
        ushortx4 p;
        p[0] = f2bf(xe.x); p[1] = f2bf(xe.y); p[2] = f2bf(xe.z); p[3] = f2bf(xe.w);
        *(ushortx4*)(Xb + (size_t)t * DH + fi * 4) = p;
#pragma unroll
        for (int e = 0; e < NEXP; e++) {
            float4 we = wv[e * 256 + fi];
            acc[e] += xe.x * we.x + xe.y * we.y + xe.z * we.z + xe.w * we.w;
        }
    }
#pragma unroll
    for (int e = 0; e < NEXP; e++) {
#pragma unroll
        for (int off = 32; off > 0; off >>= 1)
            acc[e] += __shfl_xor(acc[e], off, 64);
    }
    if (lane == 0) {
        float v0 = -1e30f, v1 = -1e30f;
        int i0 = 0, i1 = 0;
#pragma unroll
        for (int e = 0; e < NEXP; e++) {
            float l = acc[e];
            if (l > v0) { v1 = v0; i1 = i0; v0 = l; i0 = e; }
            else if (l > v1) { v1 = l; i1 = e; }
        }
        float e1 = __expf(v1 - v0);
        float w0 = 1.0f / (1.0f + e1);
        float w1 = e1 / (1.0f + e1);
        idx_pair[2 * t] = i0; idx_pair[2 * t + 1] = i1;
        w_pair[2 * t] = w0;   w_pair[2 * t + 1] = w1;
        atomicAdd(&cnt[i0], 1); atomicAdd(&cnt[i1], 1);
        atomicAdd(&esum[i0], w0); atomicAdd(&esum[i1], w1);
    }
}

// ---------------- prefix scan + load-balance loss ----------------
__global__ void prefix_lb_kernel(const int* __restrict__ cnt, int* __restrict__ prefix,
                                 int* __restrict__ cursor, const float* __restrict__ esum,
                                 float* __restrict__ lb_out) {
    if (threadIdx.x == 0) {
        int run = 0;
        for (int e = 0; e < NEXP; e++) { prefix[e] = run; cursor[e] = run; run += cnt[e]; }
        float mu = 0.f, us[NEXP];
        for (int e = 0; e < NEXP; e++) { us[e] = esum[e] * (1.0f / T_TOK); mu += us[e]; }
        mu *= (1.0f / NEXP);
        float var = 0.f;
        for (int e = 0; e < NEXP; e++) { float d = us[e] - mu; var += d * d; }
        var *= (1.0f / (NEXP - 1));
        lb_out[0] = 0.01f * var;
    }
}

// ---------------- scatter tokens to per-expert compact rows ----------------
__global__ __launch_bounds__(256) void scatter_kernel(
        const int* __restrict__ idx_pair, const float* __restrict__ w_pair,
        int* __restrict__ cursor, int* __restrict__ row_tok, float* __restrict__ row_w) {
    int t = blockIdx.x * 256 + threadIdx.x;
#pragma unroll
    for (int k = 0; k < 2; k++) {
        int e = idx_pair[2 * t + k];
        int slot = atomicAdd(&cursor[e], 1);
        row_tok[slot] = t;
        row_w[slot] = w_pair[2 * t + k];
    }
}

// ---------------- transpose+convert: src[E][R][C] fp32 -> dst[E][C'][R] bf16 ----------------
__global__ __launch_bounds__(256) void transpose_bf16_kernel(
        const float* __restrict__ src, unsigned short* __restrict__ dst,
        int R, int C, int colBase, int colsPerE) {
    int e = blockIdx.z;
    int c0 = colBase + blockIdx.x * 64;
    int r0 = blockIdx.y * 64;
    __shared__ float tile[64][65];
    int tx = threadIdx.x & 63, ty = threadIdx.x >> 6;
    const float* s = src + (size_t)e * R * C;
#pragma unroll
    for (int i = 0; i < 16; i++)
        tile[ty + i * 4][tx] = s[(size_t)(r0 + ty + i * 4) * C + c0 + tx];
    __syncthreads();
    unsigned short* d = dst + (size_t)e * colsPerE * R;
#pragma unroll
    for (int i = 0; i < 16; i++)
        d[(size_t)(c0 - colBase + ty + i * 4) * R + r0 + tx] = f2bf(tile[tx][ty + i * 4]);
}

// ---------------- FFN1: H = gelu(Xb[gathered] @ W1T^T + b1), m97-style ----------------
__global__ __launch_bounds__(256) void ffn1_kernel(
        const unsigned short* __restrict__ Xb, const unsigned short* __restrict__ W1T,
        const float* __restrict__ b1, const int* __restrict__ hdr,
        const int* __restrict__ row_tok, unsigned short* __restrict__ H,
        int chunkF, int fBase) {
    int e = blockIdx.z;
    int cntv = hdr[e];
    int rt = blockIdx.y;
    int valid = cntv - rt * 128;
    if (valid <= 0) return;
    if (valid > 128) valid = 128;
    int base = hdr[24 + e] + rt * 128;
    int f0 = blockIdx.x * 128;

    __shared__ unsigned short Alds[128 * 32];
    __shared__ unsigned short Blds[128 * 32];

    int tid = threadIdx.x;
    int lane = tid & 63, w = tid >> 6;
    int rloc = lane >> 2, cc = lane & 3;
    int r0 = w * 16 + rloc, r1 = 64 + w * 16 + rloc;

    int cl0 = r0 < valid ? r0 : valid - 1;
    int cl1 = r1 < valid ? r1 : valid - 1;
    int tok0 = row_tok[base + cl0];
    int tok1 = row_tok[base + cl1];
    const char* gA0 = (const char*)Xb + (size_t)tok0 * (DH * 2) + (cc ^ swz(r0)) * 16;
    const char* gA1 = (const char*)Xb + (size_t)tok1 * (DH * 2) + (cc ^ swz(r1)) * 16;
    const char* gB0 = (const char*)W1T + (size_t)(e * chunkF + f0 + r0) * (DH * 2) + (cc ^ swz(r0)) * 16;
    const char* gB1 = (const char*)W1T + (size_t)(e * chunkF + f0 + r1) * (DH * 2) + (cc ^ swz(r1)) * 16;
    char* lA0 = (char*)Alds + (w * 16) * 64;
    char* lA1 = (char*)Alds + (64 + w * 16) * 64;
    char* lB0 = (char*)Blds + (w * 16) * 64;
    char* lB1 = (char*)Blds + (64 + w * 16) * 64;

    int wm = (w & 1) * 64, wn = (w >> 1) * 64;
    int lr = lane & 15, lg = lane >> 4;
    int offA[4], offB[4];
#pragma unroll
    for (int i = 0; i < 4; i++) {
        int rr = wm + i * 16 + lr;
        offA[i] = rr * 32 + (lg ^ swz(rr)) * 8;
        int nn = wn + i * 16 + lr;
        offB[i] = nn * 32 + (lg ^ swz(nn)) * 8;
    }

    f32x4 acc[4][4];
#pragma unroll
    for (int i = 0; i < 4; i++)
#pragma unroll
        for (int j = 0; j < 4; j++) acc[i][j] = (f32x4)(0.f);

    for (int kk = 0; kk < DH / 32; kk++) {
        gl_lds16(gA0, lA0); gl_lds16(gA1, lA1);
        gl_lds16(gB0, lB0); gl_lds16(gB1, lB1);
        gA0 += 64; gA1 += 64; gB0 += 64; gB1 += 64;
        __syncthreads();
        short8 af[4], bf[4];
#pragma unroll
        for (int i = 0; i < 4; i++) af[i] = *(const short8*)&Alds[offA[i]];
#pragma unroll
        for (int j = 0; j < 4; j++) bf[j] = *(const short8*)&Blds[offB[j]];
#pragma unroll
        for (int i = 0; i < 4; i++)
#pragma unroll
            for (int j = 0; j < 4; j++)
                acc[i][j] = __builtin_amdgcn_mfma_f32_16x16x32_bf16(af[i], bf[j], acc[i][j], 0, 0, 0);
        __syncthreads();
    }

#pragma unroll
    for (int i = 0; i < 4; i++) {
#pragma unroll
        for (int r = 0; r < 4; r++) {
            int mm = wm + i * 16 + lg * 4 + r;
            if (mm < valid) {
                unsigned short* hrow = H + (size_t)(base + mm) * chunkF + f0;
#pragma unroll
                for (int j = 0; j < 4; j++) {
                    int n = wn + j * 16 + lr;
                    float v = acc[i][j][r] + b1[e * DFFN + fBase + f0 + n];
                    v = 0.5f * v * (1.0f + erff(v * 0.70710678118f));
                    hrow[n] = f2bf(v);
                }
            }
        }
    }
}

// ---------------- FFN2: out[tok] += w * (H @ W2T^T + b2), m97-style ----------------
__global__ __launch_bounds__(256) void ffn2_kernel(
        const unsigned short* __restrict__ H, const unsigned short* __restrict__ W2T,
        const float* __restrict__ b2, const int* __restrict__ hdr,
        const int* __restrict__ row_tok, const float* __restrict__ row_w,
        float* __restrict__ out, int chunkF, int cBase, int addBias) {
    int e = blockIdx.z;
    int cntv = hdr[e];
    int rt = blockIdx.y;
    int valid = cntv - rt * 128;
    if (valid <= 0) return;
    if (valid > 128) valid = 128;
    int base = hdr[24 + e] + rt * 128;
    int d0 = blockIdx.x * 128;

    __shared__ unsigned short Alds[128 * 32];
    __shared__ unsigned short Blds[128 * 32];
    __shared__ int ltok[128];
    __shared__ float lw[128];

    int tid = threadIdx.x;
    if (tid < 128) {
        bool v = tid < valid;
        ltok[tid] = v ? row_tok[base + tid] : 0;
        lw[tid] = v ? row_w[base + tid] : 0.f;
    }
    __syncthreads();

    int lane = tid & 63, w = tid >> 6;
    int rloc = lane >> 2, cc = lane & 3;
    int r0 = w * 16 + rloc, r1 = 64 + w * 16 + rloc;
    int cl0 = r0 < valid ? r0 : valid - 1;
    int cl1 = r1 < valid ? r1 : valid - 1;
    const char* gA0 = (const char*)H + (size_t)(base + cl0) * chunkF * 2 + (cc ^ swz(r0)) * 16;
    const char* gA1 = (const char*)H + (size_t)(base + cl1) * chunkF * 2 + (cc ^ swz(r1)) * 16;
    const char* gB0 = (const char*)W2T + ((size_t)(e * DH + d0 + r0) * DFFN + cBase) * 2 + (cc ^ swz(r0)) * 16;
    const char* gB1 = (const char*)W2T + ((size_t)(e * DH + d0 + r1) * DFFN + cBase) * 2 + (cc ^ swz(r1)) * 16;
    char* lA0 = (char*)Alds + (w * 16) * 64;
    char* lA1 = (char*)Alds + (64 + w * 16) * 64;
    char* lB0 = (char*)Blds + (w * 16) * 64;
    char* lB1 = (char*)Blds + (64 + w * 16) * 64;

    int wm = (w & 1) * 64, wn = (w >> 1) * 64;
    int lr = lane & 15, lg = lane >> 4;
    int offA[4], offB[4];
#pragma unroll
    for (int i = 0; i < 4; i++) {
        int rr = wm + i * 16 + lr;
        offA[i] = rr * 32 + (lg ^ swz(rr)) * 8;
        int nn = wn + i * 16 + lr;
        offB[i] = nn * 32 + (lg ^ swz(nn)) * 8;
    }

    f32x4 acc[4][4];
#pragma unroll
    for (int i = 0; i < 4; i++)
#pragma unroll
        for (int j = 0; j < 4; j++) acc[i][j] = (f32x4)(0.f);

    int ksteps = chunkF / 32;
    for (int kk = 0; kk < ksteps; kk++) {
        gl_lds16(gA0, lA0); gl_lds16(gA1, lA1);
        gl_lds16(gB0, lB0); gl_lds16(gB1, lB1);
        gA0 += 64; gA1 += 64; gB0 += 64; gB1 += 64;
        __syncthreads();
        short8 af[4], bf[4];
#pragma unroll
        for (int i = 0; i < 4; i++) af[i] = *(const short8*)&Alds[offA[i]];
#pragma unroll
        for (int j = 0; j < 4; j++) bf[j] = *(const short8*)&Blds[offB[j]];
#pragma unroll
        for (int i = 0; i < 4; i++)
#pragma unroll
            for (int j = 0; j < 4; j++)
                acc[i][j] = __builtin_amdgcn_mfma_f32_16x16x32_bf16(af[i], bf[j], acc[i][j], 0, 0, 0);
        __syncthreads();
    }

#pragma unroll
    for (int i = 0; i < 4; i++) {
#pragma unroll
        for (int r = 0; r < 4; r++) {
            int mm = wm + i * 16 + lg * 4 + r;
            if (mm < valid) {
                int tok = ltok[mm];
                float wgt = lw[mm];
                float* orow = out + (size_t)tok * DH + d0;
#pragma unroll
                for (int j = 0; j < 4; j++) {
                    int n = wn + j * 16 + lr;
                    float v = acc[i][j][r];
                    if (addBias) v += b2[e * DH + d0 + n];
                    unsafeAtomicAdd(&orow[n], wgt * v);
                }
            }
        }
    }
}

extern "C" void kernel_launch(void* const* d_in, const int* in_sizes, int n_in,
                              void* d_out, int out_size, void* d_ws, size_t ws_size,
                              hipStream_t stream) {
    const float* x  = (const float*)d_in[0];
    const float* Wg = (const float*)d_in[1];
    const float* W1 = (const float*)d_in[2];
    const float* b1 = (const float*)d_in[3];
    const float* W2 = (const float*)d_in[4];
    const float* b2 = (const float*)d_in[5];
    float* out = (float*)d_out;
    char* ws = (char*)d_ws;

    int* cnt      = (int*)(ws + WS_COUNT);
    int* cursor   = (int*)(ws + WS_CURSOR);
    float* esum   = (float*)(ws + WS_ESUM);
    int* prefix   = (int*)(ws + WS_PREFIX);
    int* idx_pair = (int*)(ws + WS_IDX);
    float* w_pair = (float*)(ws + WS_WPAIR);
    int* row_tok  = (int*)(ws + WS_ROWTOK);
    float* row_w  = (float*)(ws + WS_ROWW);
    unsigned short* Xb = (unsigned short*)(ws + WS_XB);

    size_t off_w2t = WS_XB + (size_t)T_TOK * DH * 2;                 // +16 MB
    size_t off_w1t = off_w2t + (size_t)NEXP * DFFN * DH * 2;         // +64 MB
    // pick smallest chunking NC such that W1T-chunk + H-chunk fit in ws
    int NC = 1;
    while (NC < 8) {
        size_t need = off_w1t + ((size_t)NEXP * DFFN * DH * 2) / NC
                              + ((size_t)2 * T_TOK * DFFN * 2) / NC;
        if (need <= ws_size) break;
        NC *= 2;
    }
    int chunkF = DFFN / NC;
    unsigned short* W2T = (unsigned short*)(ws + off_w2t);
    unsigned short* W1T = (unsigned short*)(ws + off_w1t);
    unsigned short* Hc  = (unsigned short*)(ws + off_w1t + (size_t)NEXP * chunkF * DH * 2);

    hipMemsetAsync(ws, 0, 128, stream);
    hipMemsetAsync(d_out, 0, (size_t)out_size * sizeof(float), stream);

    gate_kernel<<<T_TOK / 4, 256, 0, stream>>>(x, Wg, cnt, esum, idx_pair, w_pair, Xb);
    prefix_lb_kernel<<<1, 64, 0, stream>>>(cnt, prefix, cursor, esum,
                                           out + (size_t)T_TOK * DH);
    scatter_kernel<<<T_TOK / 256, 256, 0, stream>>>(idx_pair, w_pair, cursor, row_tok, row_w);
    // W2 [E][DFFN][DH] -> W2T [E][DH][DFFN] bf16
    transpose_bf16_kernel<<<dim3(DH / 64, DFFN / 64, NEXP), 256, 0, stream>>>(
        W2, W2T, DFFN, DH, 0, DH);

    const int* hdr = (const int*)ws;
    for (int c = 0; c < NC; c++) {
        // W1 [E][DH][DFFN] cols [c*chunkF, ...) -> W1T [E][chunkF][DH] bf16
        transpose_bf16_kernel<<<dim3(chunkF / 64, DH / 64, NEXP), 256, 0, stream>>>(
            W1, W1T, DH, DFFN, c * chunkF, chunkF);
        ffn1_kernel<<<dim3(chunkF / 128, T_TOK / 128, NEXP), 256, 0, stream>>>(
            Xb, W1T, b1, hdr, row_tok, Hc, chunkF, c * chunkF);
        ffn2_kernel<<<dim3(DH / 128, T_TOK / 128, NEXP), 256, 0, stream>>>(
            Hc, W2T, b2, hdr, row_tok, row_w, out, chunkF, c * chunkF, c == 0);
    }
}

// Round 3
// 1191.472 us; speedup vs baseline: 1.0792x; 1.0083x over previous
//
#include <hip/hip_runtime.h>
#include <hip/hip_bf16.h>
#include <math.h>

#define T_TOK 8192
#define DH 1024
#define DFFN 4096
#define NEXP 8
#define MAXT 136           // max padded tiles (128 + 7) rounded up
#define MAXROWS 17536      // max padded row slots

typedef __attribute__((ext_vector_type(8))) short short8;
typedef __attribute__((ext_vector_type(4))) float f32x4;
typedef __attribute__((ext_vector_type(4))) unsigned short ushortx4;

typedef const __attribute__((address_space(1))) void* gp1_t;
typedef __attribute__((address_space(3))) void* lp3_t;

__device__ __forceinline__ void gl_lds16(const void* g, void* l) {
    __builtin_amdgcn_global_load_lds((gp1_t)g, (lp3_t)l, 16, 0, 0);
}

__device__ __forceinline__ int swz(int r) { return (r ^ (r >> 2)) & 3; }

__device__ __forceinline__ unsigned short f2bf(float f) {
    unsigned u = __float_as_uint(f);
    u += 0x7fffu + ((u >> 16) & 1u);   // RNE
    return (unsigned short)(u >> 16);
}

// ---------------- ws header layout (ints) ----------------
// hdr[0]      n_tiles
// hdr[8..15]  cnt[8]        (memset 0)
// hdr[16..23] cursor[8]
// hdr[24..31] pbase[8]
// hdr[32..39] esum (float)  (memset 0)
// hdr[64..]   tmap[MAXT]  packed: e | (valid<<4) | (base<<16)
#define WS_IDX     1024                 // int[2*T_TOK]
#define WS_WPAIR   (WS_IDX + 65536)     // float[2*T_TOK]
#define WS_ROWTOK  (WS_WPAIR + 65536)   // int[MAXROWS]
#define WS_ROWW    (WS_ROWTOK + 4*MAXROWS)
#define WS_XB      524288               // bf16[8192][1024] = 16 MB

// ---------------- gating: one wave per token; also emits x as bf16 ----------------
__global__ __launch_bounds__(256) void gate_kernel(
        const float* __restrict__ x, const float* __restrict__ Wg,
        int* __restrict__ hdr, float* __restrict__ esum,
        int* __restrict__ idx_pair, float* __restrict__ w_pair,
        unsigned short* __restrict__ Xb) {
    int wid = threadIdx.x >> 6, lane = threadIdx.x & 63;
    int t = blockIdx.x * 4 + wid;
    const float4* xv = (const float4*)(x + (size_t)t * DH);
    const float4* wv = (const float4*)Wg;
    float acc[NEXP];
#pragma unroll
    for (int e = 0; e < NEXP; e++) acc[e] = 0.f;
#pragma unroll
    for (int c = 0; c < 4; c++) {
        int fi = c * 64 + lane;
        float4 xe = xv[fi];
        ushortx4 p;
        p[0] = f2bf(xe.x); p[1] = f2bf(xe.y); p[2] = f2bf(xe.z); p[3] = f2bf(xe.w);
        *(ushortx4*)(Xb + (size_t)t * DH + fi * 4) = p;
#pragma unroll
        for (int e = 0; e < NEXP; e++) {
            float4 we = wv[e * 256 + fi];
            acc[e] += xe.x * we.x + xe.y * we.y + xe.z * we.z + xe.w * we.w;
        }
    }
#pragma unroll
    for (int e = 0; e < NEXP; e++) {
#pragma unroll
        for (int off = 32; off > 0; off >>= 1)
            acc[e] += __shfl_xor(acc[e], off, 64);
    }
    if (lane == 0) {
        float v0 = -1e30f, v1 = -1e30f;
        int i0 = 0, i1 = 0;
#pragma unroll
        for (int e = 0; e < NEXP; e++) {
            float l = acc[e];
            if (l > v0) { v1 = v0; i1 = i0; v0 = l; i0 = e; }
            else if (l > v1) { v1 = l; i1 = e; }
        }
        float e1 = __expf(v1 - v0);
        float w0 = 1.0f / (1.0f + e1);
        float w1 = e1 / (1.0f + e1);
        idx_pair[2 * t] = i0; idx_pair[2 * t + 1] = i1;
        w_pair[2 * t] = w0;   w_pair[2 * t + 1] = w1;
        atomicAdd(&hdr[8 + i0], 1); atomicAdd(&hdr[8 + i1], 1);
        atomicAdd(&esum[i0], w0); atomicAdd(&esum[i1], w1);
    }
}

// ---------------- prefix scan + tile map + load-balance loss ----------------
__global__ void prefix_lb_kernel(int* __restrict__ hdr, const float* __restrict__ esum,
                                 float* __restrict__ lb_out) {
    if (threadIdx.x == 0) {
        int run = 0, tiles = 0;
        for (int e = 0; e < NEXP; e++) {
            int c = hdr[8 + e];
            hdr[16 + e] = run;   // cursor
            hdr[24 + e] = run;   // pbase
            int nt = (c + 127) >> 7;
            for (int t = 0; t < nt; t++) {
                int valid = c - t * 128; if (valid > 128) valid = 128;
                hdr[64 + tiles++] = e | (valid << 4) | ((run + t * 128) << 16);
            }
            run += nt * 128;
        }
        hdr[0] = tiles;
        float mu = 0.f, us[NEXP];
        for (int e = 0; e < NEXP; e++) { us[e] = esum[e] * (1.0f / T_TOK); mu += us[e]; }
        mu *= (1.0f / NEXP);
        float var = 0.f;
        for (int e = 0; e < NEXP; e++) { float d = us[e] - mu; var += d * d; }
        var *= (1.0f / (NEXP - 1));
        lb_out[0] = 0.01f * var;
    }
}

// ---------------- scatter tokens to per-expert compact rows ----------------
__global__ __launch_bounds__(256) void scatter_kernel(
        const int* __restrict__ idx_pair, const float* __restrict__ w_pair,
        int* __restrict__ hdr, int* __restrict__ row_tok, float* __restrict__ row_w) {
    int t = blockIdx.x * 256 + threadIdx.x;
#pragma unroll
    for (int k = 0; k < 2; k++) {
        int e = idx_pair[2 * t + k];
        int slot = atomicAdd(&hdr[16 + e], 1);
        row_tok[slot] = t;
        row_w[slot] = w_pair[2 * t + k];
    }
}

// ---------------- transpose+convert: src[E][R][C] fp32 -> dst[E][C'][R] bf16 ----------------
__global__ __launch_bounds__(256) void transpose_bf16_kernel(
        const float* __restrict__ src, unsigned short* __restrict__ dst,
        int R, int C, int colBase, int colsPerE) {
    int e = blockIdx.z;
    int c0 = colBase + blockIdx.x * 64;
    int r0 = blockIdx.y * 64;
    __shared__ float tile[64][65];
    int tx = threadIdx.x & 63, ty = threadIdx.x >> 6;
    const float* s = src + (size_t)e * R * C;
#pragma unroll
    for (int i = 0; i < 16; i++)
        tile[ty + i * 4][tx] = s[(size_t)(r0 + ty + i * 4) * C + c0 + tx];
    __syncthreads();
    unsigned short* d = dst + (size_t)e * colsPerE * R;
#pragma unroll
    for (int i = 0; i < 16; i++)
        d[(size_t)(c0 - colBase + ty + i * 4) * R + r0 + tx] = f2bf(tile[tx][ty + i * 4]);
}

// ---------------- FFN1: H = gelu(Xb[gathered] @ W1T^T + b1) ----------------
__global__ __launch_bounds__(256) void ffn1_kernel(
        const unsigned short* __restrict__ Xb, const unsigned short* __restrict__ W1T,
        const float* __restrict__ b1, const int* __restrict__ hdr,
        const int* __restrict__ row_tok, unsigned short* __restrict__ H,
        int chunkF, int fBase) {
    int tile = blockIdx.y;
    if (tile >= hdr[0]) return;
    int tm = hdr[64 + tile];
    int e = tm & 15, valid = (tm >> 4) & 255, base = tm >> 16;
    int f0 = blockIdx.x * 128;

    __shared__ unsigned short Alds[128 * 32];
    __shared__ unsigned short Blds[128 * 32];

    int tid = threadIdx.x;
    int lane = tid & 63, w = tid >> 6;
    int rloc = lane >> 2, cc = lane & 3;
    int r0 = w * 16 + rloc, r1 = 64 + w * 16 + rloc;

    int cl0 = r0 < valid ? r0 : valid - 1;
    int cl1 = r1 < valid ? r1 : valid - 1;
    int tok0 = row_tok[base + cl0];
    int tok1 = row_tok[base + cl1];
    const char* gA0 = (const char*)Xb + (size_t)tok0 * (DH * 2) + (cc ^ swz(r0)) * 16;
    const char* gA1 = (const char*)Xb + (size_t)tok1 * (DH * 2) + (cc ^ swz(r1)) * 16;
    const char* gB0 = (const char*)W1T + (size_t)(e * chunkF + f0 + r0) * (DH * 2) + (cc ^ swz(r0)) * 16;
    const char* gB1 = (const char*)W1T + (size_t)(e * chunkF + f0 + r1) * (DH * 2) + (cc ^ swz(r1)) * 16;
    char* lA0 = (char*)Alds + (w * 16) * 64;
    char* lA1 = (char*)Alds + (64 + w * 16) * 64;
    char* lB0 = (char*)Blds + (w * 16) * 64;
    char* lB1 = (char*)Blds + (64 + w * 16) * 64;

    int wm = (w & 1) * 64, wn = (w >> 1) * 64;
    int lr = lane & 15, lg = lane >> 4;
    int offA[4], offB[4];
#pragma unroll
    for (int i = 0; i < 4; i++) {
        int rr = wm + i * 16 + lr;
        offA[i] = rr * 32 + (lg ^ swz(rr)) * 8;
        int nn = wn + i * 16 + lr;
        offB[i] = nn * 32 + (lg ^ swz(nn)) * 8;
    }

    f32x4 acc[4][4];
#pragma unroll
    for (int i = 0; i < 4; i++)
#pragma unroll
        for (int j = 0; j < 4; j++) acc[i][j] = (f32x4)(0.f);

    for (int kk = 0; kk < DH / 32; kk++) {
        gl_lds16(gA0, lA0); gl_lds16(gA1, lA1);
        gl_lds16(gB0, lB0); gl_lds16(gB1, lB1);
        gA0 += 64; gA1 += 64; gB0 += 64; gB1 += 64;
        __syncthreads();
        short8 af[4], bf[4];
#pragma unroll
        for (int i = 0; i < 4; i++) af[i] = *(const short8*)&Alds[offA[i]];
#pragma unroll
        for (int j = 0; j < 4; j++) bf[j] = *(const short8*)&Blds[offB[j]];
#pragma unroll
        for (int i = 0; i < 4; i++)
#pragma unroll
            for (int j = 0; j < 4; j++)
                acc[i][j] = __builtin_amdgcn_mfma_f32_16x16x32_bf16(af[i], bf[j], acc[i][j], 0, 0, 0);
        __syncthreads();
    }

#pragma unroll
    for (int i = 0; i < 4; i++) {
#pragma unroll
        for (int r = 0; r < 4; r++) {
            int mm = wm + i * 16 + lg * 4 + r;
            if (mm < valid) {
                unsigned short* hrow = H + (size_t)(base + mm) * chunkF + f0;
#pragma unroll
                for (int j = 0; j < 4; j++) {
                    int n = wn + j * 16 + lr;
                    float v = acc[i][j][r] + b1[e * DFFN + fBase + f0 + n];
                    v = 0.5f * v * (1.0f + erff(v * 0.70710678118f));
                    hrow[n] = f2bf(v);
                }
            }
        }
    }
}

// ---------------- FFN2: out[tok] += w * (H @ W2T^T + b2) ----------------
__global__ __launch_bounds__(256) void ffn2_kernel(
        const unsigned short* __restrict__ H, const unsigned short* __restrict__ W2T,
        const float* __restrict__ b2, const int* __restrict__ hdr,
        const int* __restrict__ row_tok, const float* __restrict__ row_w,
        float* __restrict__ out, int chunkF, int cBase, int addBias) {
    int tile = blockIdx.y;
    if (tile >= hdr[0]) return;
    int tm = hdr[64 + tile];
    int e = tm & 15, valid = (tm >> 4) & 255, base = tm >> 16;
    int d0 = blockIdx.x * 128;

    __shared__ unsigned short Alds[128 * 32];
    __shared__ unsigned short Blds[128 * 32];
    __shared__ int ltok[128];
    __shared__ float lw[128];

    int tid = threadIdx.x;
    if (tid < 128) {
        bool v = tid < valid;
        ltok[tid] = v ? row_tok[base + tid] : 0;
        lw[tid] = v ? row_w[base + tid] : 0.f;
    }
    __syncthreads();

    int lane = tid & 63, w = tid >> 6;
    int rloc = lane >> 2, cc = lane & 3;
    int r0 = w * 16 + rloc, r1 = 64 + w * 16 + rloc;
    int cl0 = r0 < valid ? r0 : valid - 1;
    int cl1 = r1 < valid ? r1 : valid - 1;
    const char* gA0 = (const char*)H + (size_t)(base + cl0) * chunkF * 2 + (cc ^ swz(r0)) * 16;
    const char* gA1 = (const char*)H + (size_t)(base + cl1) * chunkF * 2 + (cc ^ swz(r1)) * 16;
    const char* gB0 = (const char*)W2T + ((size_t)(e * DH + d0 + r0) * DFFN + cBase) * 2 + (cc ^ swz(r0)) * 16;
    const char* gB1 = (const char*)W2T + ((size_t)(e * DH + d0 + r1) * DFFN + cBase) * 2 + (cc ^ swz(r1)) * 16;
    char* lA0 = (char*)Alds + (w * 16) * 64;
    char* lA1 = (char*)Alds + (64 + w * 16) * 64;
    char* lB0 = (char*)Blds + (w * 16) * 64;
    char* lB1 = (char*)Blds + (64 + w * 16) * 64;

    int wm = (w & 1) * 64, wn = (w >> 1) * 64;
    int lr = lane & 15, lg = lane >> 4;
    int offA[4], offB[4];
#pragma unroll
    for (int i = 0; i < 4; i++) {
        int rr = wm + i * 16 + lr;
        offA[i] = rr * 32 + (lg ^ swz(rr)) * 8;
        int nn = wn + i * 16 + lr;
        offB[i] = nn * 32 + (lg ^ swz(nn)) * 8;
    }

    f32x4 acc[4][4];
#pragma unroll
    for (int i = 0; i < 4; i++)
#pragma unroll
        for (int j = 0; j < 4; j++) acc[i][j] = (f32x4)(0.f);

    int ksteps = chunkF / 32;
    for (int kk = 0; kk < ksteps; kk++) {
        gl_lds16(gA0, lA0); gl_lds16(gA1, lA1);
        gl_lds16(gB0, lB0); gl_lds16(gB1, lB1);
        gA0 += 64; gA1 += 64; gB0 += 64; gB1 += 64;
        __syncthreads();
        short8 af[4], bf[4];
#pragma unroll
        for (int i = 0; i < 4; i++) af[i] = *(const short8*)&Alds[offA[i]];
#pragma unroll
        for (int j = 0; j < 4; j++) bf[j] = *(const short8*)&Blds[offB[j]];
#pragma unroll
        for (int i = 0; i < 4; i++)
#pragma unroll
            for (int j = 0; j < 4; j++)
                acc[i][j] = __builtin_amdgcn_mfma_f32_16x16x32_bf16(af[i], bf[j], acc[i][j], 0, 0, 0);
        __syncthreads();
    }

#pragma unroll
    for (int i = 0; i < 4; i++) {
#pragma unroll
        for (int r = 0; r < 4; r++) {
            int mm = wm + i * 16 + lg * 4 + r;
            if (mm < valid) {
                int tok = ltok[mm];
                float wgt = lw[mm];
                float* orow = out + (size_t)tok * DH + d0;
#pragma unroll
                for (int j = 0; j < 4; j++) {
                    int n = wn + j * 16 + lr;
                    float v = acc[i][j][r];
                    if (addBias) v += b2[e * DH + d0 + n];
                    unsafeAtomicAdd(&orow[n], wgt * v);
                }
            }
        }
    }
}

extern "C" void kernel_launch(void* const* d_in, const int* in_sizes, int n_in,
                              void* d_out, int out_size, void* d_ws, size_t ws_size,
                              hipStream_t stream) {
    const float* x  = (const float*)d_in[0];
    const float* Wg = (const float*)d_in[1];
    const float* W1 = (const float*)d_in[2];
    const float* b1 = (const float*)d_in[3];
    const float* W2 = (const float*)d_in[4];
    const float* b2 = (const float*)d_in[5];
    float* out = (float*)d_out;
    char* ws = (char*)d_ws;

    int* hdr      = (int*)ws;
    float* esum   = (float*)(hdr + 32);
    int* idx_pair = (int*)(ws + WS_IDX);
    float* w_pair = (float*)(ws + WS_WPAIR);
    int* row_tok  = (int*)(ws + WS_ROWTOK);
    float* row_w  = (float*)(ws + WS_ROWW);
    unsigned short* Xb = (unsigned short*)(ws + WS_XB);

    size_t off_w2t = WS_XB + (size_t)T_TOK * DH * 2;                 // +16 MB
    size_t off_w1t = off_w2t + (size_t)NEXP * DFFN * DH * 2;         // +64 MB
    int NC = 1;
    while (NC < 8) {
        size_t need = off_w1t + ((size_t)NEXP * DFFN * DH * 2) / NC
                              + ((size_t)MAXROWS * DFFN * 2) / NC;
        if (need <= ws_size) break;
        NC *= 2;
    }
    int chunkF = DFFN / NC;
    unsigned short* W2T = (unsigned short*)(ws + off_w2t);
    unsigned short* W1T = (unsigned short*)(ws + off_w1t);
    unsigned short* Hc  = (unsigned short*)(ws + off_w1t + (size_t)NEXP * chunkF * DH * 2);

    hipMemsetAsync(ws, 0, 1024, stream);
    hipMemsetAsync(d_out, 0, (size_t)out_size * sizeof(float), stream);

    gate_kernel<<<T_TOK / 4, 256, 0, stream>>>(x, Wg, hdr, esum, idx_pair, w_pair, Xb);
    prefix_lb_kernel<<<1, 64, 0, stream>>>(hdr, esum, out + (size_t)T_TOK * DH);
    scatter_kernel<<<T_TOK / 256, 256, 0, stream>>>(idx_pair, w_pair, hdr, row_tok, row_w);
    // W2 [E][DFFN][DH] -> W2T [E][DH][DFFN] bf16
    transpose_bf16_kernel<<<dim3(DH / 64, DFFN / 64, NEXP), 256, 0, stream>>>(
        W2, W2T, DFFN, DH, 0, DH);

    for (int c = 0; c < NC; c++) {
        // W1 [E][DH][DFFN] cols [c*chunkF, ...) -> W1T [E][chunkF][DH] bf16
        transpose_bf16_kernel<<<dim3(chunkF / 64, DH / 64, NEXP), 256, 0, stream>>>(
            W1, W1T, DH, DFFN, c * chunkF, chunkF);
        ffn1_kernel<<<dim3(chunkF / 128, MAXT), 256, 0, stream>>>(
            Xb, W1T, b1, hdr, row_tok, Hc, chunkF, c * chunkF);
        ffn2_kernel<<<dim3(DH / 128, MAXT), 256, 0, stream>>>(
            Hc, W2T, b2, hdr, row_tok, row_w, out, chunkF, c * chunkF, c == 0);
    }
}

// Round 4
// 1137.838 us; speedup vs baseline: 1.1301x; 1.0471x over previous
//
#include <hip/hip_runtime.h>
#include <hip/hip_bf16.h>
#include <math.h>

#define T_TOK 8192
#define DH 1024
#define DFFN 4096
#define NEXP 8
#define MAXT 136           // 8 XCD-chunks of 17 tiles
#define MAXROWS 17536      // max padded row slots

typedef __attribute__((ext_vector_type(8))) short short8;
typedef __attribute__((ext_vector_type(4))) float f32x4;
typedef __attribute__((ext_vector_type(4))) unsigned short ushortx4;

typedef const __attribute__((address_space(1))) void* gp1_t;
typedef __attribute__((address_space(3))) void* lp3_t;

__device__ __forceinline__ void gl_lds16(const void* g, void* l) {
    __builtin_amdgcn_global_load_lds((gp1_t)g, (lp3_t)l, 16, 0, 0);
}

__device__ __forceinline__ int swz(int r) { return (r ^ (r >> 2)) & 3; }

__device__ __forceinline__ unsigned short f2bf(float f) {
    unsigned u = __float_as_uint(f);
    u += 0x7fffu + ((u >> 16) & 1u);   // RNE
    return (unsigned short)(u >> 16);
}

// s_waitcnt immediates (gfx9 encoding): lgkmcnt=15(no wait), expcnt=7(no wait)
#define WAITCNT_VM4 0xF74
#define WAITCNT_VM0 0xF70

// ---------------- ws header layout (ints) ----------------
// hdr[0] n_tiles | hdr[8..15] cnt | hdr[16..23] cursor | hdr[24..31] pbase
// hdr[32..39] esum(float) | hdr[64..] tmap[MAXT]: e | valid<<4 | base<<16
#define WS_IDX     1024
#define WS_WPAIR   (WS_IDX + 65536)
#define WS_SLOT    (WS_WPAIR + 65536)
#define WS_ROWTOK  (WS_SLOT + 65536)
#define WS_ROWW    (WS_ROWTOK + 4*MAXROWS)
#define WS_XB      524288               // bf16[8192][1024] = 16 MB

// ---------------- gating: one wave per token; also emits x as bf16 ----------------
__global__ __launch_bounds__(256) void gate_kernel(
        const float* __restrict__ x, const float* __restrict__ Wg,
        int* __restrict__ hdr, float* __restrict__ esum,
        int* __restrict__ idx_pair, float* __restrict__ w_pair,
        unsigned short* __restrict__ Xb) {
    int wid = threadIdx.x >> 6, lane = threadIdx.x & 63;
    int t = blockIdx.x * 4 + wid;
    const float4* xv = (const float4*)(x + (size_t)t * DH);
    const float4* wv = (const float4*)Wg;
    float acc[NEXP];
#pragma unroll
    for (int e = 0; e < NEXP; e++) acc[e] = 0.f;
#pragma unroll
    for (int c = 0; c < 4; c++) {
        int fi = c * 64 + lane;
        float4 xe = xv[fi];
        ushortx4 p;
        p[0] = f2bf(xe.x); p[1] = f2bf(xe.y); p[2] = f2bf(xe.z); p[3] = f2bf(xe.w);
        *(ushortx4*)(Xb + (size_t)t * DH + fi * 4) = p;
#pragma unroll
        for (int e = 0; e < NEXP; e++) {
            float4 we = wv[e * 256 + fi];
            acc[e] += xe.x * we.x + xe.y * we.y + xe.z * we.z + xe.w * we.w;
        }
    }
#pragma unroll
    for (int e = 0; e < NEXP; e++) {
#pragma unroll
        for (int off = 32; off > 0; off >>= 1)
            acc[e] += __shfl_xor(acc[e], off, 64);
    }
    if (lane == 0) {
        float v0 = -1e30f, v1 = -1e30f;
        int i0 = 0, i1 = 0;
#pragma unroll
        for (int e = 0; e < NEXP; e++) {
            float l = acc[e];
            if (l > v0) { v1 = v0; i1 = i0; v0 = l; i0 = e; }
            else if (l > v1) { v1 = l; i1 = e; }
        }
        float e1 = __expf(v1 - v0);
        float w0 = 1.0f / (1.0f + e1);
        float w1 = e1 / (1.0f + e1);
        idx_pair[2 * t] = i0; idx_pair[2 * t + 1] = i1;
        w_pair[2 * t] = w0;   w_pair[2 * t + 1] = w1;
        atomicAdd(&hdr[8 + i0], 1); atomicAdd(&hdr[8 + i1], 1);
        atomicAdd(&esum[i0], w0); atomicAdd(&esum[i1], w1);
    }
}

// ---------------- prefix scan + tile map + load-balance loss ----------------
__global__ void prefix_lb_kernel(int* __restrict__ hdr, const float* __restrict__ esum,
                                 float* __restrict__ lb_out) {
    if (threadIdx.x == 0) {
        int run = 0, tiles = 0;
        for (int e = 0; e < NEXP; e++) {
            int c = hdr[8 + e];
            hdr[16 + e] = run;
            hdr[24 + e] = run;
            int nt = (c + 127) >> 7;
            for (int t = 0; t < nt; t++) {
                int valid = c - t * 128; if (valid > 128) valid = 128;
                hdr[64 + tiles++] = e | (valid << 4) | ((run + t * 128) << 16);
            }
            run += nt * 128;
        }
        hdr[0] = tiles;
        float mu = 0.f, us[NEXP];
        for (int e = 0; e < NEXP; e++) { us[e] = esum[e] * (1.0f / T_TOK); mu += us[e]; }
        mu *= (1.0f / NEXP);
        float var = 0.f;
        for (int e = 0; e < NEXP; e++) { float d = us[e] - mu; var += d * d; }
        var *= (1.0f / (NEXP - 1));
        lb_out[0] = 0.01f * var;
    }
}

// ---------------- scatter: compact rows + record slot per (token,k) ----------------
__global__ __launch_bounds__(256) void scatter_kernel(
        const int* __restrict__ idx_pair, const float* __restrict__ w_pair,
        int* __restrict__ hdr, int* __restrict__ row_tok, float* __restrict__ row_w,
        int* __restrict__ slot_pair) {
    int t = blockIdx.x * 256 + threadIdx.x;
#pragma unroll
    for (int k = 0; k < 2; k++) {
        int e = idx_pair[2 * t + k];
        int slot = atomicAdd(&hdr[16 + e], 1);
        row_tok[slot] = t;
        row_w[slot] = w_pair[2 * t + k];
        slot_pair[2 * t + k] = slot;
    }
}

// ---------------- transpose+convert: src[E][R][C] fp32 -> dst[E][C'][R] bf16 ----------------
__global__ __launch_bounds__(256) void transpose_bf16_kernel(
        const float* __restrict__ src, unsigned short* __restrict__ dst,
        int R, int C, int colBase, int colsPerE) {
    int e = blockIdx.z;
    int c0 = colBase + blockIdx.x * 64;
    int r0 = blockIdx.y * 64;
    __shared__ float tile[64][65];
    int tx = threadIdx.x & 63, ty = threadIdx.x >> 6;
    const float* s = src + (size_t)e * R * C;
#pragma unroll
    for (int i = 0; i < 16; i++)
        tile[ty + i * 4][tx] = s[(size_t)(r0 + ty + i * 4) * C + c0 + tx];
    __syncthreads();
    unsigned short* d = dst + (size_t)e * colsPerE * R;
#pragma unroll
    for (int i = 0; i < 16; i++)
        d[(size_t)(c0 - colBase + ty + i * 4) * R + r0 + tx] = f2bf(tile[tx][ty + i * 4]);
}

// ---------------- FFN1: H = gelu(Xb[gathered] @ W1T^T + b1), dbuf + XCD-chunked ----------------
__global__ __launch_bounds__(256) void ffn1_kernel(
        const unsigned short* __restrict__ Xb, const unsigned short* __restrict__ W1T,
        const float* __restrict__ b1, const int* __restrict__ hdr,
        const int* __restrict__ row_tok, unsigned short* __restrict__ H,
        int chunkF, int fBase, int fsh) {
    int lin = blockIdx.x;
    int xcd = lin & 7, pos = lin >> 3;
    int tile = xcd * 17 + (pos >> fsh);
    int fidx = pos & ((1 << fsh) - 1);
    if (tile >= hdr[0]) return;
    int tm = hdr[64 + tile];
    int e = tm & 15, valid = (tm >> 4) & 255, base = tm >> 16;
    int f0 = fidx * 128;

    __shared__ unsigned short Alds[2 * 128 * 32];
    __shared__ unsigned short Blds[2 * 128 * 32];

    int tid = threadIdx.x;
    int lane = tid & 63, w = tid >> 6;
    int rloc = lane >> 2, cc = lane & 3;
    int r0 = w * 16 + rloc, r1 = 64 + w * 16 + rloc;

    int cl0 = r0 < valid ? r0 : valid - 1;
    int cl1 = r1 < valid ? r1 : valid - 1;
    int tok0 = row_tok[base + cl0];
    int tok1 = row_tok[base + cl1];
    const char* gA0 = (const char*)Xb + (size_t)tok0 * (DH * 2) + (cc ^ swz(r0)) * 16;
    const char* gA1 = (const char*)Xb + (size_t)tok1 * (DH * 2) + (cc ^ swz(r1)) * 16;
    const char* gB0 = (const char*)W1T + (size_t)(e * chunkF + f0 + r0) * (DH * 2) + (cc ^ swz(r0)) * 16;
    const char* gB1 = (const char*)W1T + (size_t)(e * chunkF + f0 + r1) * (DH * 2) + (cc ^ swz(r1)) * 16;
    int lo0 = (w * 16) * 64, lo1 = (64 + w * 16) * 64;

    int wm = (w & 1) * 64, wn = (w >> 1) * 64;
    int lr = lane & 15, lg = lane >> 4;
    int offA[4], offB[4];
#pragma unroll
    for (int i = 0; i < 4; i++) {
        int rr = wm + i * 16 + lr;
        offA[i] = rr * 32 + (lg ^ swz(rr)) * 8;
        int nn = wn + i * 16 + lr;
        offB[i] = nn * 32 + (lg ^ swz(nn)) * 8;
    }

    f32x4 acc[4][4];
#pragma unroll
    for (int i = 0; i < 4; i++)
#pragma unroll
        for (int j = 0; j < 4; j++) acc[i][j] = (f32x4)(0.f);

    auto issue = [&](int pb) {
        char* la = (char*)Alds + pb * 8192;
        char* lb = (char*)Blds + pb * 8192;
        gl_lds16(gA0, la + lo0); gl_lds16(gA1, la + lo1);
        gl_lds16(gB0, lb + lo0); gl_lds16(gB1, lb + lo1);
        gA0 += 64; gA1 += 64; gB0 += 64; gB1 += 64;
    };

    issue(0);
    const int steps = DH / 32;
    for (int kk = 0; kk < steps; kk++) {
        int p = kk & 1;
        issue(p ^ 1);
        __builtin_amdgcn_s_waitcnt(WAITCNT_VM4);
        __builtin_amdgcn_s_barrier();
        const unsigned short* Ab = Alds + p * 4096;
        const unsigned short* Bb = Blds + p * 4096;
        short8 af[4], bf[4];
#pragma unroll
        for (int i = 0; i < 4; i++) af[i] = *(const short8*)&Ab[offA[i]];
#pragma unroll
        for (int j = 0; j < 4; j++) bf[j] = *(const short8*)&Bb[offB[j]];
#pragma unroll
        for (int i = 0; i < 4; i++)
#pragma unroll
            for (int j = 0; j < 4; j++)
                acc[i][j] = __builtin_amdgcn_mfma_f32_16x16x32_bf16(af[i], bf[j], acc[i][j], 0, 0, 0);
        __builtin_amdgcn_s_barrier();
    }
    __builtin_amdgcn_s_waitcnt(WAITCNT_VM0);

#pragma unroll
    for (int i = 0; i < 4; i++) {
#pragma unroll
        for (int r = 0; r < 4; r++) {
            int mm = wm + i * 16 + lg * 4 + r;
            if (mm < valid) {
                unsigned short* hrow = H + (size_t)(base + mm) * chunkF + f0;
#pragma unroll
                for (int j = 0; j < 4; j++) {
                    int n = wn + j * 16 + lr;
                    float v = acc[i][j][r] + b1[e * DFFN + fBase + f0 + n];
                    v = 0.5f * v * (1.0f + erff(v * 0.70710678118f));
                    hrow[n] = f2bf(v);
                }
            }
        }
    }
}

// ---------------- FFN2: Y[slot] (+)= H @ W2T^T (+ b2), dbuf + XCD-chunked ----------------
__global__ __launch_bounds__(256) void ffn2_kernel(
        const unsigned short* __restrict__ H, const unsigned short* __restrict__ W2T,
        const float* __restrict__ b2, const int* __restrict__ hdr,
        float* __restrict__ Y, int chunkF, int cBase, int firstChunk) {
    int lin = blockIdx.x;
    int xcd = lin & 7, pos = lin >> 3;
    int tile = xcd * 17 + (pos >> 3);
    int didx = pos & 7;
    if (tile >= hdr[0]) return;
    int tm = hdr[64 + tile];
    int e = tm & 15, valid = (tm >> 4) & 255, base = tm >> 16;
    int d0 = didx * 128;

    __shared__ unsigned short Alds[2 * 128 * 32];
    __shared__ unsigned short Blds[2 * 128 * 32];

    int tid = threadIdx.x;
    int lane = tid & 63, w = tid >> 6;
    int rloc = lane >> 2, cc = lane & 3;
    int r0 = w * 16 + rloc, r1 = 64 + w * 16 + rloc;
    int cl0 = r0 < valid ? r0 : valid - 1;
    int cl1 = r1 < valid ? r1 : valid - 1;
    const char* gA0 = (const char*)H + (size_t)(base + cl0) * chunkF * 2 + (cc ^ swz(r0)) * 16;
    const char* gA1 = (const char*)H + (size_t)(base + cl1) * chunkF * 2 + (cc ^ swz(r1)) * 16;
    const char* gB0 = (const char*)W2T + ((size_t)(e * DH + d0 + r0) * DFFN + cBase) * 2 + (cc ^ swz(r0)) * 16;
    const char* gB1 = (const char*)W2T + ((size_t)(e * DH + d0 + r1) * DFFN + cBase) * 2 + (cc ^ swz(r1)) * 16;
    int lo0 = (w * 16) * 64, lo1 = (64 + w * 16) * 64;

    int wm = (w & 1) * 64, wn = (w >> 1) * 64;
    int lr = lane & 15, lg = lane >> 4;
    int offA[4], offB[4];
#pragma unroll
    for (int i = 0; i < 4; i++) {
        int rr = wm + i * 16 + lr;
        offA[i] = rr * 32 + (lg ^ swz(rr)) * 8;
        int nn = wn + i * 16 + lr;
        offB[i] = nn * 32 + (lg ^ swz(nn)) * 8;
    }

    f32x4 acc[4][4];
#pragma unroll
    for (int i = 0; i < 4; i++)
#pragma unroll
        for (int j = 0; j < 4; j++) acc[i][j] = (f32x4)(0.f);

    auto issue = [&](int pb) {
        char* la = (char*)Alds + pb * 8192;
        char* lb = (char*)Blds + pb * 8192;
        gl_lds16(gA0, la + lo0); gl_lds16(gA1, la + lo1);
        gl_lds16(gB0, lb + lo0); gl_lds16(gB1, lb + lo1);
        gA0 += 64; gA1 += 64; gB0 += 64; gB1 += 64;
    };

    issue(0);
    const int steps = chunkF / 32;
    for (int kk = 0; kk < steps; kk++) {
        int p = kk & 1;
        issue(p ^ 1);
        __builtin_amdgcn_s_waitcnt(WAITCNT_VM4);
        __builtin_amdgcn_s_barrier();
        const unsigned short* Ab = Alds + p * 4096;
        const unsigned short* Bb = Blds + p * 4096;
        short8 af[4], bf[4];
#pragma unroll
        for (int i = 0; i < 4; i++) af[i] = *(const short8*)&Ab[offA[i]];
#pragma unroll
        for (int j = 0; j < 4; j++) bf[j] = *(const short8*)&Bb[offB[j]];
#pragma unroll
        for (int i = 0; i < 4; i++)
#pragma unroll
            for (int j = 0; j < 4; j++)
                acc[i][j] = __builtin_amdgcn_mfma_f32_16x16x32_bf16(af[i], bf[j], acc[i][j], 0, 0, 0);
        __builtin_amdgcn_s_barrier();
    }
    __builtin_amdgcn_s_waitcnt(WAITCNT_VM0);

#pragma unroll
    for (int i = 0; i < 4; i++) {
#pragma unroll
        for (int r = 0; r < 4; r++) {
            int mm = wm + i * 16 + lg * 4 + r;
            if (mm < valid) {
                float* yrow = Y + (size_t)(base + mm) * DH + d0;
#pragma unroll
                for (int j = 0; j < 4; j++) {
                    int n = wn + j * 16 + lr;
                    float v = acc[i][j][r];
                    if (firstChunk) yrow[n] = v + b2[e * DH + d0 + n];
                    else            yrow[n] += v;
                }
            }
        }
    }
}

// ---------------- combine: out[t] = w0*Y[s0] + w1*Y[s1] ----------------
__global__ __launch_bounds__(256) void combine_kernel(
        const float* __restrict__ Y, const int* __restrict__ slot_pair,
        const float* __restrict__ w_pair, float* __restrict__ out) {
    int t = blockIdx.x;
    int s0 = slot_pair[2 * t], s1 = slot_pair[2 * t + 1];
    float w0 = w_pair[2 * t], w1 = w_pair[2 * t + 1];
    const float4* y0 = (const float4*)(Y + (size_t)s0 * DH);
    const float4* y1 = (const float4*)(Y + (size_t)s1 * DH);
    float4* o = (float4*)(out + (size_t)t * DH);
    int i = threadIdx.x;
    float4 a = y0[i], b = y1[i];
    float4 r;
    r.x = w0 * a.x + w1 * b.x;
    r.y = w0 * a.y + w1 * b.y;
    r.z = w0 * a.z + w1 * b.z;
    r.w = w0 * a.w + w1 * b.w;
    o[i] = r;
}

extern "C" void kernel_launch(void* const* d_in, const int* in_sizes, int n_in,
                              void* d_out, int out_size, void* d_ws, size_t ws_size,
                              hipStream_t stream) {
    const float* x  = (const float*)d_in[0];
    const float* Wg = (const float*)d_in[1];
    const float* W1 = (const float*)d_in[2];
    const float* b1 = (const float*)d_in[3];
    const float* W2 = (const float*)d_in[4];
    const float* b2 = (const float*)d_in[5];
    float* out = (float*)d_out;
    char* ws = (char*)d_ws;

    int* hdr       = (int*)ws;
    float* esum    = (float*)(hdr + 32);
    int* idx_pair  = (int*)(ws + WS_IDX);
    float* w_pair  = (float*)(ws + WS_WPAIR);
    int* slot_pair = (int*)(ws + WS_SLOT);
    int* row_tok   = (int*)(ws + WS_ROWTOK);
    float* row_w   = (float*)(ws + WS_ROWW);
    unsigned short* Xb = (unsigned short*)(ws + WS_XB);

    size_t off_w2t = WS_XB + (size_t)T_TOK * DH * 2;                 // +16 MB
    size_t off_y   = off_w2t + (size_t)NEXP * DH * DFFN * 2;         // +64 MB
    size_t off_w1t = off_y + (size_t)MAXROWS * DH * 4;               // +72 MB
    int NC = 1;
    while (NC < 8) {
        size_t need = off_w1t + ((size_t)NEXP * DFFN * DH * 2) / NC
                              + ((size_t)MAXROWS * DFFN * 2) / NC + 4096;
        if (need <= ws_size) break;
        NC *= 2;
    }
    int chunkF = DFFN / NC;
    int fcount = chunkF / 128;
    int fsh = __builtin_ctz(fcount);
    unsigned short* W2T = (unsigned short*)(ws + off_w2t);
    float* Y            = (float*)(ws + off_y);
    unsigned short* W1T = (unsigned short*)(ws + off_w1t);
    unsigned short* Hc  = (unsigned short*)(ws + off_w1t + (size_t)NEXP * chunkF * DH * 2);

    hipMemsetAsync(ws, 0, 1024, stream);

    gate_kernel<<<T_TOK / 4, 256, 0, stream>>>(x, Wg, hdr, esum, idx_pair, w_pair, Xb);
    prefix_lb_kernel<<<1, 64, 0, stream>>>(hdr, esum, out + (size_t)T_TOK * DH);
    scatter_kernel<<<T_TOK / 256, 256, 0, stream>>>(idx_pair, w_pair, hdr, row_tok, row_w,
                                                    slot_pair);
    // W2 [E][DFFN][DH] -> W2T [E][DH][DFFN] bf16
    transpose_bf16_kernel<<<dim3(DH / 64, DFFN / 64, NEXP), 256, 0, stream>>>(
        W2, W2T, DFFN, DH, 0, DH);

    for (int c = 0; c < NC; c++) {
        transpose_bf16_kernel<<<dim3(chunkF / 64, DH / 64, NEXP), 256, 0, stream>>>(
            W1, W1T, DH, DFFN, c * chunkF, chunkF);
        ffn1_kernel<<<MAXT * fcount, 256, 0, stream>>>(
            Xb, W1T, b1, hdr, row_tok, Hc, chunkF, c * chunkF, fsh);
        ffn2_kernel<<<MAXT * 8, 256, 0, stream>>>(
            Hc, W2T, b2, hdr, Y, chunkF, c * chunkF, c == 0);
    }
    combine_kernel<<<T_TOK, 256, 0, stream>>>(Y, slot_pair, w_pair, out);
}